// Round 1
// baseline (806.205 us; speedup 1.0000x reference)
//
#include <hip/hip_runtime.h>

#define TT 4096
#define HH 1024
#define EE 8
#define FF 3584

typedef _Float16 half8  __attribute__((ext_vector_type(8)));
typedef _Float16 half4v __attribute__((ext_vector_type(4)));
typedef float    f32x4  __attribute__((ext_vector_type(4)));

// layout swizzle: XOR byte-bits 4-5 of the within-row offset by s2(row),
// applied identically on LDS writes and reads (involution => consistent).
__device__ __forceinline__ int s2row(int r) { return ((r >> 2) ^ (r >> 4)) & 3; }

// ---------------------------------------------------------------------------
// Router: logits (fp32, exact), softmax, top-2 + renorm, build expert lists.
// Also casts x -> fp16 into xh. One wave per token.
// ---------------------------------------------------------------------------
__global__ __launch_bounds__(256) void router_kernel(
    const float* __restrict__ x, const float* __restrict__ rw,
    _Float16* __restrict__ xh, int* __restrict__ counts,
    int* __restrict__ tok_list, float* __restrict__ w_list)
{
    const int lane = threadIdx.x & 63;
    const int wv   = threadIdx.x >> 6;
    const int t    = blockIdx.x * 4 + wv;

    const f32x4* x4  = (const f32x4*)(x + (size_t)t * HH);
    const f32x4* rw4 = (const f32x4*)rw;

    float acc[EE];
#pragma unroll
    for (int e = 0; e < EE; e++) acc[e] = 0.f;

#pragma unroll
    for (int i = 0; i < 4; i++) {
        f32x4 v = x4[i * 64 + lane];
        half4v o;
        o[0] = (_Float16)v[0]; o[1] = (_Float16)v[1];
        o[2] = (_Float16)v[2]; o[3] = (_Float16)v[3];
        *(half4v*)(xh + (size_t)t * HH + (size_t)(i * 64 + lane) * 4) = o;
#pragma unroll
        for (int e = 0; e < EE; e++) {
            f32x4 w = rw4[e * 256 + i * 64 + lane];
            acc[e] += v[0] * w[0] + v[1] * w[1] + v[2] * w[2] + v[3] * w[3];
        }
    }
#pragma unroll
    for (int e = 0; e < EE; e++) {
#pragma unroll
        for (int off = 32; off; off >>= 1) acc[e] += __shfl_xor(acc[e], off);
    }
    if (lane == 0) {
        float mx = acc[0];
#pragma unroll
        for (int e = 1; e < EE; e++) mx = fmaxf(mx, acc[e]);
        float p[EE];
#pragma unroll
        for (int e = 0; e < EE; e++) p[e] = __expf(acc[e] - mx);
        int i0 = 0; float b0 = p[0];
#pragma unroll
        for (int e = 1; e < EE; e++) { if (p[e] > b0) { b0 = p[e]; i0 = e; } }
        int i1 = -1; float b1 = -1.f;
#pragma unroll
        for (int e = 0; e < EE; e++) { if (e != i0 && p[e] > b1) { b1 = p[e]; i1 = e; } }
        float inv = 1.f / (b0 + b1);
        int p0 = atomicAdd(&counts[i0], 1);
        tok_list[i0 * TT + p0] = t; w_list[i0 * TT + p0] = b0 * inv;
        int p1 = atomicAdd(&counts[i1], 1);
        tok_list[i1 * TT + p1] = t; w_list[i1 * TT + p1] = b1 * inv;
    }
}

__global__ void scan_kernel(const int* __restrict__ counts, int* __restrict__ offsets)
{
    if (threadIdx.x == 0) {
        int s = 0;
        for (int e = 0; e < EE; e++) { offsets[e] = s; s += counts[e]; }
        offsets[EE] = s;
    }
}

// ---------------------------------------------------------------------------
// 128x128 tile GEMM K-loop. A: fp16 rows via per-lane global ptrs (gather ok).
// B: fp32 weights, converted to fp16 in-register during staging, stored
// transposed [n][k] in LDS (stride 40 halves + XOR swizzle). One barrier
// per K-step, double-buffered LDS, loads issued 2 steps ahead.
// ---------------------------------------------------------------------------
template <int NK, int BSTRIDE>
__device__ __forceinline__ void gemm_tile(
    const _Float16* __restrict__ gA0, const _Float16* __restrict__ gA1,
    const float* __restrict__ gB,
    _Float16 (*Al)[5120], _Float16 (*Bl)[5120],
    f32x4 (&acc)[4][4])
{
    const int tid  = threadIdx.x;
    const int lane = tid & 63;
    const int wv   = tid >> 6;
    const int wm   = (wv >> 1) * 64, wn = (wv & 1) * 64;
    const int rA0  = tid >> 2, kgA = tid & 3;
    const int nB4  = (tid & 31) * 4, kqB = tid >> 5;

    // precomputed LDS offsets (constant across K-steps)
    const int wa0 = rA0 * 40 + ((kgA ^ s2row(rA0)) << 3);
    const int wa1 = (64 + rA0) * 40 + ((kgA ^ s2row(64 + rA0)) << 3);
    int wb[4];
#pragma unroll
    for (int j = 0; j < 4; j++) {
        int row = nB4 + j;
        wb[j] = row * 40 + ((kqB ^ (s2row(row) << 1)) << 2);
    }
    int aoff[4], boff[4];
#pragma unroll
    for (int i = 0; i < 4; i++) {
        int ar = wm + i * 16 + (lane & 15);
        aoff[i] = ar * 40 + (((lane >> 4) ^ s2row(ar)) << 3);
        int br = wn + i * 16 + (lane & 15);
        boff[i] = br * 40 + (((lane >> 4) ^ s2row(br)) << 3);
    }

    half8 sa0, sa1;
    f32x4 sw0, sw1, sw2, sw3;

    auto LOAD = [&](int ks) {
        sa0 = *(const half8*)(gA0 + ks * 32);
        sa1 = *(const half8*)(gA1 + ks * 32);
        const float* b = gB + (size_t)ks * 32 * BSTRIDE;
        sw0 = *(const f32x4*)b;
        sw1 = *(const f32x4*)(b + BSTRIDE);
        sw2 = *(const f32x4*)(b + 2 * BSTRIDE);
        sw3 = *(const f32x4*)(b + 3 * BSTRIDE);
    };
    auto WRITE = [&](int buf) {
        *(half8*)&Al[buf][wa0] = sa0;
        *(half8*)&Al[buf][wa1] = sa1;
#pragma unroll
        for (int j = 0; j < 4; j++) {
            half4v pk;
            pk[0] = (_Float16)sw0[j]; pk[1] = (_Float16)sw1[j];
            pk[2] = (_Float16)sw2[j]; pk[3] = (_Float16)sw3[j];
            *(half4v*)&Bl[buf][wb[j]] = pk;
        }
    };

    LOAD(0);
    WRITE(0);
    LOAD(1);
    __syncthreads();

    for (int ks = 0; ks < NK; ks++) {
        const int cur = ks & 1;
        if (ks + 1 < NK) WRITE(cur ^ 1);
        if (ks + 2 < NK) LOAD(ks + 2);

        half8 af[4];
#pragma unroll
        for (int mi = 0; mi < 4; mi++)
            af[mi] = *(const half8*)&Al[cur][aoff[mi]];
#pragma unroll
        for (int ni = 0; ni < 4; ni++) {
            half8 bfr = *(const half8*)&Bl[cur][boff[ni]];
#pragma unroll
            for (int mi = 0; mi < 4; mi++)
                acc[mi][ni] = __builtin_amdgcn_mfma_f32_16x16x32_f16(
                    af[mi], bfr, acc[mi][ni], 0, 0, 0);
        }
        __syncthreads();
    }
}

// ---------------------------------------------------------------------------
// Phase A: per expert, gathered rows. Two passes (gate, then up) sharing the
// accumulator registers; silu(g) parked in fp16 regs between passes.
// Writes h = silu(g)*u (fp16) to compact hbuf rows.
// ---------------------------------------------------------------------------
__global__ __launch_bounds__(256, 2) void ffn_gu_kernel(
    const _Float16* __restrict__ xh,
    const float* __restrict__ wg, const float* __restrict__ wu,
    const int* __restrict__ tok_list, const int* __restrict__ counts,
    const int* __restrict__ offsets, _Float16* __restrict__ hbuf)
{
    const int e   = blockIdx.z;
    const int cnt = counts[e];
    const int m0  = blockIdx.y * 128;
    if (m0 >= cnt) return;
    const int n0  = blockIdx.x * 128;
    const int off = offsets[e];
    const int tid = threadIdx.x;
    const int lane = tid & 63;
    const int wv   = tid >> 6;
    const int wm   = (wv >> 1) * 64, wn = (wv & 1) * 64;

    const int rA0 = tid >> 2, kgA = tid & 3;
    int g0 = m0 + rA0;      if (g0 > cnt - 1) g0 = cnt - 1;
    int g1 = m0 + 64 + rA0; if (g1 > cnt - 1) g1 = cnt - 1;
    const _Float16* gA0 = xh + (size_t)tok_list[e * TT + g0] * HH + kgA * 8;
    const _Float16* gA1 = xh + (size_t)tok_list[e * TT + g1] * HH + kgA * 8;
    const int nB4 = (tid & 31) * 4, kqB = tid >> 5;

    __shared__ _Float16 Al[2][5120];
    __shared__ _Float16 Bl[2][5120];

    f32x4 acc[4][4];
#pragma unroll
    for (int i = 0; i < 4; i++)
#pragma unroll
        for (int j = 0; j < 4; j++) acc[i][j] = f32x4{0.f, 0.f, 0.f, 0.f};

    const float* gBg = wg + (size_t)e * HH * FF + (size_t)kqB * 4 * FF + n0 + nB4;
    gemm_tile<HH / 32, FF>(gA0, gA1, gBg, Al, Bl, acc);

    half4v park[4][4];
#pragma unroll
    for (int mi = 0; mi < 4; mi++)
#pragma unroll
        for (int ni = 0; ni < 4; ni++) {
#pragma unroll
            for (int r = 0; r < 4; r++) {
                float g = acc[mi][ni][r];
                float s = g / (1.f + __expf(-g));
                park[mi][ni][r] = (_Float16)s;
            }
            acc[mi][ni] = f32x4{0.f, 0.f, 0.f, 0.f};
        }

    const float* gBu = wu + (size_t)e * HH * FF + (size_t)kqB * 4 * FF + n0 + nB4;
    gemm_tile<HH / 32, FF>(gA0, gA1, gBu, Al, Bl, acc);

#pragma unroll
    for (int mi = 0; mi < 4; mi++) {
#pragma unroll
        for (int r = 0; r < 4; r++) {
            int trow = m0 + wm + mi * 16 + ((lane >> 4) << 2) + r;
            if (trow < cnt) {
                _Float16* dst = hbuf + (size_t)(off + trow) * FF + n0 + wn + (lane & 15);
#pragma unroll
                for (int ni = 0; ni < 4; ni++) {
                    float hv = (float)park[mi][ni][r] * acc[mi][ni][r];
                    dst[ni * 16] = (_Float16)hv;
                }
            }
        }
    }
}

// ---------------------------------------------------------------------------
// Phase B: y = h @ w_down[e]; scatter w_tok * y into out via atomicAdd.
// ---------------------------------------------------------------------------
__global__ __launch_bounds__(256, 2) void ffn_down_kernel(
    const _Float16* __restrict__ hbuf, const float* __restrict__ wd,
    const int* __restrict__ tok_list, const float* __restrict__ w_list,
    const int* __restrict__ counts, const int* __restrict__ offsets,
    float* __restrict__ out)
{
    const int e   = blockIdx.z;
    const int cnt = counts[e];
    const int m0  = blockIdx.y * 128;
    if (m0 >= cnt) return;
    const int n0  = blockIdx.x * 128;
    const int off = offsets[e];
    const int tid = threadIdx.x;
    const int lane = tid & 63;
    const int wv   = tid >> 6;
    const int wm   = (wv >> 1) * 64, wn = (wv & 1) * 64;

    const int rA0 = tid >> 2, kgA = tid & 3;
    int g0 = m0 + rA0;      if (g0 > cnt - 1) g0 = cnt - 1;
    int g1 = m0 + 64 + rA0; if (g1 > cnt - 1) g1 = cnt - 1;
    const _Float16* gA0 = hbuf + (size_t)(off + g0) * FF + kgA * 8;
    const _Float16* gA1 = hbuf + (size_t)(off + g1) * FF + kgA * 8;
    const int nB4 = (tid & 31) * 4, kqB = tid >> 5;

    __shared__ _Float16 Al[2][5120];
    __shared__ _Float16 Bl[2][5120];

    f32x4 acc[4][4];
#pragma unroll
    for (int i = 0; i < 4; i++)
#pragma unroll
        for (int j = 0; j < 4; j++) acc[i][j] = f32x4{0.f, 0.f, 0.f, 0.f};

    const float* gBd = wd + (size_t)e * FF * HH + (size_t)kqB * 4 * HH + n0 + nB4;
    gemm_tile<FF / 32, HH>(gA0, gA1, gBd, Al, Bl, acc);

#pragma unroll
    for (int mi = 0; mi < 4; mi++) {
#pragma unroll
        for (int r = 0; r < 4; r++) {
            int trow = m0 + wm + mi * 16 + ((lane >> 4) << 2) + r;
            if (trow < cnt) {
                int tok = tok_list[e * TT + trow];
                float w = w_list[e * TT + trow];
                float* dst = out + (size_t)tok * HH + n0 + wn + (lane & 15);
#pragma unroll
                for (int ni = 0; ni < 4; ni++)
                    atomicAdd(dst + ni * 16, w * acc[mi][ni][r]);
            }
        }
    }
}

// ---------------------------------------------------------------------------
extern "C" void kernel_launch(void* const* d_in, const int* in_sizes, int n_in,
                              void* d_out, int out_size, void* d_ws, size_t ws_size,
                              hipStream_t stream)
{
    const float* x  = (const float*)d_in[0];
    const float* rw = (const float*)d_in[1];
    const float* wg = (const float*)d_in[2];
    const float* wu = (const float*)d_in[3];
    const float* wd = (const float*)d_in[4];
    float* out = (float*)d_out;

    char* ws = (char*)d_ws;
    int*      counts   = (int*)(ws + 0);            // 32 B
    int*      offsets  = (int*)(ws + 64);           // 36 B
    int*      tok_list = (int*)(ws + 1024);         // 128 KiB
    float*    w_list   = (float*)(ws + 1024 + 131072);
    _Float16* xh       = (_Float16*)(ws + 263168);  // 8 MiB
    _Float16* hbuf     = (_Float16*)(ws + 8651776); // 56 MiB

    hipMemsetAsync(counts, 0, 64, stream);
    hipMemsetAsync(out, 0, (size_t)TT * HH * sizeof(float), stream);

    router_kernel<<<TT / 4, 256, 0, stream>>>(x, rw, xh, counts, tok_list, w_list);
    scan_kernel<<<1, 64, 0, stream>>>(counts, offsets);
    ffn_gu_kernel<<<dim3(FF / 128, TT / 128, EE), 256, 0, stream>>>(
        xh, wg, wu, tok_list, counts, offsets, hbuf);
    ffn_down_kernel<<<dim3(HH / 128, TT / 128, EE), 256, 0, stream>>>(
        hbuf, wd, tok_list, w_list, counts, offsets, out);
}